// Round 7
// baseline (231.444 us; speedup 1.0000x reference)
//
#include <hip/hip_runtime.h>
#include <hip/hip_bf16.h>

#define NTOT 8192
#define FIN 128
#define FOUT 32
#define NH 4
#define NSEG 4
#define SEGJ (NTOT / NSEG)  // 2048
#define LOG2E 1.4426950408889634f

typedef __attribute__((ext_vector_type(4))) float f32x4;
typedef __attribute__((ext_vector_type(4))) unsigned int u32x4;
typedef __attribute__((ext_vector_type(8))) __bf16 bf16x8;
typedef unsigned long long u64;
typedef unsigned int u32;

__device__ __forceinline__ unsigned short f2bf(float x) {
  __hip_bfloat16 h = __float2bfloat16(x);
  return *reinterpret_cast<unsigned short*>(&h);
}

__device__ __forceinline__ float fexp2(float y) {
  float p;
  asm("v_exp_f32 %0, %1" : "=v"(p) : "v"(y));
  return p;
}

// ---------------- k0: bit-pack adj -> bits64T[j64][i] (u64 per (row,64j)), 8 MB
__global__ __launch_bounds__(512, 2) void k0_pack(
    const int* __restrict__ adj, u64* __restrict__ bits64T) {
  int row = blockIdx.x * 8 + (threadIdx.x >> 6);
  int l = threadIdx.x & 63;
  const int* ap = adj + (size_t)row * NTOT + l;
  u64* bp = bits64T + row;
#pragma unroll 4
  for (int j64 = 0; j64 < NTOT / 64; ++j64) {
    int v = ap[j64 * 64];
    u64 mske = __ballot(v != 0);
    if (l == 0) bp[(size_t)j64 * NTOT] = mske;
  }
}

// ---------------- k1: h = X @ W -> h [N][128] f32, plus B-fragment panels:
// panel[(p*256 + jt)*512 + l*8 + e] (bf16), p = hd*2+half,
//   value = h[node = jt*32 + (l>>4)*8 + e][p*16 + (l&15)]
__global__ __launch_bounds__(256, 2) void k1_project(
    const float* __restrict__ X, const float* __restrict__ W,
    float* __restrict__ h, unsigned short* __restrict__ panel) {
  __shared__ float Xs[32 * 128];
  __shared__ float Ws[32 * 128];
  __shared__ unsigned short Hs[128 * 40];  // [o][node_local], stride 40
  int t = threadIdx.x;
  int nb = blockIdx.x * 32;

  const f32x4* Xg = reinterpret_cast<const f32x4*>(X + (size_t)nb * FIN);
  f32x4* Xs4 = reinterpret_cast<f32x4*>(Xs);
#pragma unroll
  for (int r = 0; r < 4; ++r) Xs4[t + r * 256] = Xg[t + r * 256];

  int ng = t >> 5, oq = t & 31;
  int n0 = ng * 4, o0 = oq * 4;
  f32x4 acc[4];
#pragma unroll
  for (int nn = 0; nn < 4; ++nn) acc[nn] = (f32x4){0.f, 0.f, 0.f, 0.f};

  for (int kp = 0; kp < 4; ++kp) {
    __syncthreads();
#pragma unroll
    for (int r = 0; r < 4; ++r) {
      int q = t + r * 256;
      int flat = q * 4;
      int kk = flat >> 7;
      int c = flat & 127;
      int hdd = c >> 5;
      int oo = c & 31;
      *reinterpret_cast<f32x4*>(&Ws[kk * 128 + c]) =
          *reinterpret_cast<const f32x4*>(W + hdd * (FIN * FOUT) +
                                          (kp * 32 + kk) * FOUT + oo);
    }
    __syncthreads();
#pragma unroll 8
    for (int kk = 0; kk < 32; ++kk) {
      f32x4 wv = *reinterpret_cast<const f32x4*>(&Ws[kk * 128 + o0]);
#pragma unroll
      for (int nn = 0; nn < 4; ++nn)
        acc[nn] += Xs[(n0 + nn) * 128 + kp * 32 + kk] * wv;
    }
  }
#pragma unroll
  for (int nn = 0; nn < 4; ++nn) {
    *reinterpret_cast<f32x4*>(&h[(size_t)(nb + n0 + nn) * 128 + o0]) = acc[nn];
#pragma unroll
    for (int c = 0; c < 4; ++c)
      Hs[(o0 + c) * 40 + (n0 + nn)] = f2bf(acc[nn][c]);
  }
  __syncthreads();
  int jt = blockIdx.x;
#pragma unroll
  for (int it = 0; it < 2; ++it) {
    int item = t + it * 256;
    int p = item >> 6;
    int l = item & 63;
    int o = p * 16 + (l & 15);
    u32x4 v = *reinterpret_cast<const u32x4*>(&Hs[o * 40 + (l >> 4) * 8]);
    *reinterpret_cast<u32x4*>(panel + (size_t)(p * 256 + jt) * 512 + l * 8) = v;
  }
}

// ---------------- k2: per-node scores, pre-scaled by log2(e)
__global__ __launch_bounds__(256, 2) void k2_scores(
    const float* __restrict__ h, const float* __restrict__ a_src,
    const float* __restrict__ a_dst, float* __restrict__ Sl2,
    float* __restrict__ Dl2) {
  int n = blockIdx.x * 256 + threadIdx.x;
  const f32x4* hv = reinterpret_cast<const f32x4*>(h + (size_t)n * 128);
  const f32x4* as4 = reinterpret_cast<const f32x4*>(a_src);
  const f32x4* ad4 = reinterpret_cast<const f32x4*>(a_dst);
#pragma unroll
  for (int hd = 0; hd < NH; ++hd) {
    f32x4 sa = {0.f, 0.f, 0.f, 0.f}, da = {0.f, 0.f, 0.f, 0.f};
#pragma unroll
    for (int q = 0; q < 8; ++q) {
      f32x4 x = hv[hd * 8 + q];
      sa += x * as4[hd * 8 + q];
      da += x * ad4[hd * 8 + q];
    }
    float s = (sa[0] + sa[1]) + (sa[2] + sa[3]);
    float d = (da[0] + da[1]) + (da[2] + da[3]);
    Sl2[hd * NTOT + n] = s * LOG2E;
    Dl2[hd * NTOT + n] = d * LOG2E;
  }
}

// ---------------- k3: fused masked softmax + PV. M=32 rows/wave, no LDS,
// in-register adjacency masks, exp2-direct, 2-deep pipeline PINNED with
// sched_barrier(0) so the compiler cannot sink the prefetch loads.
__global__ __launch_bounds__(512, 4) void k3_attn(
    const u64* __restrict__ bits64T, const float* __restrict__ Sl2,
    const float* __restrict__ Dl2, const unsigned short* __restrict__ panel,
    float* __restrict__ pacc, float* __restrict__ plsum) {
  const int N = NTOT;
  int tid = threadIdx.x;
  int w = tid >> 6, l = tid & 63;
  int hd = w & 3, isub = w >> 2;
  int itile = blockIdx.x >> 2, seg = blockIdx.x & 3;
  int ibase = itile * 64 + isub * 32;
  int m = l & 15, jc = (l >> 4) * 8;
  int i0 = ibase + m, i1 = i0 + 16;

  float sv0 = Sl2[hd * N + i0], sv1 = Sl2[hd * N + i1];
  const float* dbase = Dl2 + hd * N + seg * SEGJ + jc;
  const u64* bptr = bits64T + (size_t)(seg * (SEGJ / 64)) * N;
  const unsigned short* pan0 =
      panel + (size_t)((hd * 2 + 0) * 256 + seg * (SEGJ / 32)) * 512 + l * 8;
  const unsigned short* pan1 = pan0 + (size_t)256 * 512;

  f32x4 z4 = {0.f, 0.f, 0.f, 0.f};
  f32x4 acc0[2] = {z4, z4}, acc1[2] = {z4, z4}, acc2[2] = {z4, z4};
  bf16x8 bones;
  {
    u32 pat = (m == 0) ? 0x3f803f80u : 0u;
    u32x4 tmp = {pat, pat, pat, pat};
    bones = *reinterpret_cast<bf16x8*>(&tmp);
  }

#define K3_ISSUE(P, mi_)                                            \
  {                                                                 \
    int mi__ = (mi_);                                               \
    P##w0 = bptr[(size_t)mi__ * N + i0];                            \
    P##w1 = bptr[(size_t)mi__ * N + i1];                            \
    const float* da_ = dbase + mi__ * 64;                           \
    P##d0 = *reinterpret_cast<const f32x4*>(da_);                   \
    P##d1 = *reinterpret_cast<const f32x4*>(da_ + 4);               \
    P##d2 = *reinterpret_cast<const f32x4*>(da_ + 32);              \
    P##d3 = *reinterpret_cast<const f32x4*>(da_ + 36);              \
    const unsigned short* pa_ = pan0 + mi__ * 1024;                 \
    P##p0 = *reinterpret_cast<const bf16x8*>(pa_);                  \
    P##p1 = *reinterpret_cast<const bf16x8*>(pa_ + 512);            \
    const unsigned short* pb_ = pan1 + mi__ * 1024;                 \
    P##q0 = *reinterpret_cast<const bf16x8*>(pb_);                  \
    P##q1 = *reinterpret_cast<const bf16x8*>(pb_ + 512);            \
  }                                                                 \
  __builtin_amdgcn_sched_barrier(0);

  // build masked A-frag for one (8-j, row-group): by = adjacency byte
#define K3_AF(AF, BY, DA, DB, SV)                                        \
  {                                                                      \
    f32x4 xa_ = (DA) + (SV);                                             \
    f32x4 xb_ = (DB) + (SV);                                             \
    f32x4 ya_ = __builtin_elementwise_max(xa_, 0.2f * xa_);              \
    f32x4 yb_ = __builtin_elementwise_max(xb_, 0.2f * xb_);              \
    bf16x8 af_;                                                          \
    _Pragma("unroll") for (int e = 0; e < 4; ++e) af_[e] =               \
        (__bf16)fexp2(ya_[e]);                                           \
    _Pragma("unroll") for (int e = 0; e < 4; ++e) af_[e + 4] =           \
        (__bf16)fexp2(yb_[e]);                                           \
    u32x4 mk_;                                                           \
    _Pragma("unroll") for (int p = 0; p < 4; ++p) {                      \
      u32 lo_ = (u32)(((int)((BY) << (31 - 2 * p))) >> 31);              \
      u32 hi_ = (u32)(((int)((BY) << (30 - 2 * p))) >> 31);              \
      mk_[p] = __builtin_amdgcn_perm(hi_, lo_, 0x07060100u);             \
    }                                                                    \
    u32x4 av_ = *reinterpret_cast<u32x4*>(&af_) & mk_;                   \
    AF = *reinterpret_cast<bf16x8*>(&av_);                               \
  }

#define K3_RG(AF, B0, B1, RG)                                                 \
  acc0[RG] = __builtin_amdgcn_mfma_f32_16x16x32_bf16(AF, (B0), acc0[RG], 0,   \
                                                     0, 0);                   \
  acc1[RG] = __builtin_amdgcn_mfma_f32_16x16x32_bf16(AF, (B1), acc1[RG], 0,   \
                                                     0, 0);                   \
  acc2[RG] = __builtin_amdgcn_mfma_f32_16x16x32_bf16(AF, bones, acc2[RG], 0,  \
                                                     0, 0);

#define K3_COMP(P)                                         \
  {                                                        \
    bf16x8 af_r;                                           \
    u32 by_;                                               \
    by_ = ((u32)(P##w0) >> jc) & 0xFFu;                    \
    K3_AF(af_r, by_, P##d0, P##d1, sv0)                    \
    K3_RG(af_r, P##p0, P##q0, 0)                           \
    by_ = ((u32)(P##w1) >> jc) & 0xFFu;                    \
    K3_AF(af_r, by_, P##d0, P##d1, sv1)                    \
    K3_RG(af_r, P##p0, P##q0, 1)                           \
    by_ = ((u32)(P##w0 >> 32) >> jc) & 0xFFu;              \
    K3_AF(af_r, by_, P##d2, P##d3, sv0)                    \
    K3_RG(af_r, P##p1, P##q1, 0)                           \
    by_ = ((u32)(P##w1 >> 32) >> jc) & 0xFFu;              \
    K3_AF(af_r, by_, P##d2, P##d3, sv1)                    \
    K3_RG(af_r, P##p1, P##q1, 1)                           \
  }

  u64 Aw0, Aw1, Bw0, Bw1;
  f32x4 Ad0, Ad1, Ad2, Ad3, Bd0, Bd1, Bd2, Bd3;
  bf16x8 Ap0, Ap1, Aq0, Aq1, Bp0, Bp1, Bq0, Bq1;

  K3_ISSUE(A, 0)
  K3_ISSUE(B, 1)
#pragma unroll 1
  for (int tt = 0; tt < 16; ++tt) {
    int tA = 2 * tt + 2, tB = 2 * tt + 3;
    if (tA > 31) tA = 31;
    if (tB > 31) tB = 31;
    K3_COMP(A)
    K3_ISSUE(A, tA)
    K3_COMP(B)
    K3_ISSUE(B, tB)
  }
#undef K3_ISSUE
#undef K3_AF
#undef K3_RG
#undef K3_COMP

  // epilogue: D layout col=lane&15 (o), row=(lane>>4)*4+reg (i)
#pragma unroll
  for (int rg = 0; rg < 2; ++rg) {
    int rb = ibase + rg * 16 + ((l >> 4) << 2);
    if (m == 0) {
#pragma unroll
      for (int r = 0; r < 4; ++r)
        plsum[(seg * NH + hd) * N + rb + r] = acc2[rg][r];
    }
#pragma unroll
    for (int r = 0; r < 4; ++r) {
      int row = rb + r;
      pacc[((size_t)seg * N + row) * 128 + hd * 32 + m] = acc0[rg][r];
      pacc[((size_t)seg * N + row) * 128 + hd * 32 + 16 + m] = acc1[rg][r];
    }
  }
}

// ---------------- k4: combine segments + normalize
__global__ __launch_bounds__(256, 2) void k4_combine(
    const float* __restrict__ pacc, const float* __restrict__ plsum,
    float* __restrict__ out) {
  int idx = blockIdx.x * 256 + threadIdx.x;
  int i = idx >> 7;
  int c = idx & 127;
  int hd = c >> 5;
  float a = 0.f, ls = 0.f;
#pragma unroll
  for (int s = 0; s < NSEG; ++s) {
    a += pacc[((size_t)s * NTOT + i) * 128 + c];
    ls += plsum[(s * NH + hd) * NTOT + i];
  }
  out[idx] = (ls > 0.f) ? a / ls : 0.f;
}

extern "C" void kernel_launch(void* const* d_in, const int* in_sizes, int n_in,
                              void* d_out, int out_size, void* d_ws,
                              size_t ws_size, hipStream_t stream) {
  const float* X = (const float*)d_in[0];
  const int* adj = (const int*)d_in[1];
  const float* W = (const float*)d_in[2];
  const float* a_src = (const float*)d_in[3];
  const float* a_dst = (const float*)d_in[4];
  float* out = (float*)d_out;

  char* ws = (char*)d_ws;
  float* h = (float*)(ws + 0x0);                             // 4 MB
  unsigned short* panel = (unsigned short*)(ws + 0x400000);  // 2 MB
  float* Sl2 = (float*)(ws + 0x600000);                      // 128 KB
  float* Dl2 = (float*)(ws + 0x620000);                      // 128 KB
  u64* bits64T = (u64*)(ws + 0x640000);                      // 8 MB
  float* pacc = (float*)(ws + 0xE40000);                     // 16 MB
  float* plsum = (float*)(ws + 0x1E40000);                   // 512 KB

  k0_pack<<<dim3(1024), dim3(512), 0, stream>>>(adj, bits64T);
  k1_project<<<dim3(256), dim3(256), 0, stream>>>(X, W, h, panel);
  k2_scores<<<dim3(32), dim3(256), 0, stream>>>(h, a_src, a_dst, Sl2, Dl2);
  k3_attn<<<dim3(128 * NSEG), dim3(512), 0, stream>>>(bits64T, Sl2, Dl2,
                                                      panel, pacc, plsum);
  k4_combine<<<dim3(4096), dim3(256), 0, stream>>>(pacc, plsum, out);
}

// Round 8
// 178.335 us; speedup vs baseline: 1.2978x; 1.2978x over previous
//
#include <hip/hip_runtime.h>
#include <hip/hip_bf16.h>

#define NTOT 8192
#define FIN 128
#define FOUT 32
#define NH 4
#define NSEG 4
#define LOG2E 1.4426950408889634f
#define BUFB 18432  // per-buffer LDS bytes: panel 16K @0, Dt 1K @16384, bits 512B @17408

typedef __attribute__((ext_vector_type(4))) float f32x4;
typedef __attribute__((ext_vector_type(4))) unsigned int u32x4;
typedef __attribute__((ext_vector_type(8))) __bf16 bf16x8;
typedef unsigned long long u64;
typedef unsigned int u32;

__device__ __forceinline__ unsigned short f2bf(float x) {
  __hip_bfloat16 h = __float2bfloat16(x);
  return *reinterpret_cast<unsigned short*>(&h);
}

__device__ __forceinline__ float fexp2(float y) {
  float p;
  asm("v_exp_f32 %0, %1" : "=v"(p) : "v"(y));
  return p;
}

// ---------------- k0: bit-pack adj -> bits64T[j64][i] (u64 per (row,64j)), 8 MB
__global__ __launch_bounds__(512, 2) void k0_pack(
    const int* __restrict__ adj, u64* __restrict__ bits64T) {
  int row = blockIdx.x * 8 + (threadIdx.x >> 6);
  int l = threadIdx.x & 63;
  const int* ap = adj + (size_t)row * NTOT + l;
  u64* bp = bits64T + row;
#pragma unroll 4
  for (int j64 = 0; j64 < NTOT / 64; ++j64) {
    int v = ap[j64 * 64];
    u64 mske = __ballot(v != 0);
    if (l == 0) bp[(size_t)j64 * NTOT] = mske;
  }
}

// ---------------- k1: h = X @ W -> h [N][128] f32, plus B-fragment panels:
// panel[(p*256 + jt)*512 + l*8 + e] (bf16), p = hd*2+half,
//   value = h[node = jt*32 + (l>>4)*8 + e][p*16 + (l&15)]
__global__ __launch_bounds__(256, 2) void k1_project(
    const float* __restrict__ X, const float* __restrict__ W,
    float* __restrict__ h, unsigned short* __restrict__ panel) {
  __shared__ float Xs[32 * 128];
  __shared__ float Ws[32 * 128];
  __shared__ unsigned short Hs[128 * 40];  // [o][node_local], stride 40
  int t = threadIdx.x;
  int nb = blockIdx.x * 32;

  const f32x4* Xg = reinterpret_cast<const f32x4*>(X + (size_t)nb * FIN);
  f32x4* Xs4 = reinterpret_cast<f32x4*>(Xs);
#pragma unroll
  for (int r = 0; r < 4; ++r) Xs4[t + r * 256] = Xg[t + r * 256];

  int ng = t >> 5, oq = t & 31;
  int n0 = ng * 4, o0 = oq * 4;
  f32x4 acc[4];
#pragma unroll
  for (int nn = 0; nn < 4; ++nn) acc[nn] = (f32x4){0.f, 0.f, 0.f, 0.f};

  for (int kp = 0; kp < 4; ++kp) {
    __syncthreads();
#pragma unroll
    for (int r = 0; r < 4; ++r) {
      int q = t + r * 256;
      int flat = q * 4;
      int kk = flat >> 7;
      int c = flat & 127;
      int hdd = c >> 5;
      int oo = c & 31;
      *reinterpret_cast<f32x4*>(&Ws[kk * 128 + c]) =
          *reinterpret_cast<const f32x4*>(W + hdd * (FIN * FOUT) +
                                          (kp * 32 + kk) * FOUT + oo);
    }
    __syncthreads();
#pragma unroll 8
    for (int kk = 0; kk < 32; ++kk) {
      f32x4 wv = *reinterpret_cast<const f32x4*>(&Ws[kk * 128 + o0]);
#pragma unroll
      for (int nn = 0; nn < 4; ++nn)
        acc[nn] += Xs[(n0 + nn) * 128 + kp * 32 + kk] * wv;
    }
  }
#pragma unroll
  for (int nn = 0; nn < 4; ++nn) {
    *reinterpret_cast<f32x4*>(&h[(size_t)(nb + n0 + nn) * 128 + o0]) = acc[nn];
#pragma unroll
    for (int c = 0; c < 4; ++c)
      Hs[(o0 + c) * 40 + (n0 + nn)] = f2bf(acc[nn][c]);
  }
  __syncthreads();
  int jt = blockIdx.x;
#pragma unroll
  for (int it = 0; it < 2; ++it) {
    int item = t + it * 256;
    int p = item >> 6;
    int l = item & 63;
    int o = p * 16 + (l & 15);
    u32x4 v = *reinterpret_cast<const u32x4*>(&Hs[o * 40 + (l >> 4) * 8]);
    *reinterpret_cast<u32x4*>(panel + (size_t)(p * 256 + jt) * 512 + l * 8) = v;
  }
}

// ---------------- k2: per-node scores (x log2e). Sl2 [hd][N]; Dt [jm][hd][64]
__global__ __launch_bounds__(256, 2) void k2_scores(
    const float* __restrict__ h, const float* __restrict__ a_src,
    const float* __restrict__ a_dst, float* __restrict__ Sl2,
    float* __restrict__ Dt) {
  int n = blockIdx.x * 256 + threadIdx.x;
  const f32x4* hv = reinterpret_cast<const f32x4*>(h + (size_t)n * 128);
  const f32x4* as4 = reinterpret_cast<const f32x4*>(a_src);
  const f32x4* ad4 = reinterpret_cast<const f32x4*>(a_dst);
#pragma unroll
  for (int hd = 0; hd < NH; ++hd) {
    f32x4 sa = {0.f, 0.f, 0.f, 0.f}, da = {0.f, 0.f, 0.f, 0.f};
#pragma unroll
    for (int q = 0; q < 8; ++q) {
      f32x4 x = hv[hd * 8 + q];
      sa += x * as4[hd * 8 + q];
      da += x * ad4[hd * 8 + q];
    }
    float s = (sa[0] + sa[1]) + (sa[2] + sa[3]);
    float d = (da[0] + da[1]) + (da[2] + da[3]);
    Sl2[hd * NTOT + n] = s * LOG2E;
    Dt[(n >> 6) * 256 + hd * 64 + (n & 63)] = d * LOG2E;
  }
}

// ---------------- k3: fused masked softmax + PV. LDS double-buffered macro
// staging (panel 16K + Dt 1K + bits 512B per 64-j macro), one barrier/macro.
__global__ __launch_bounds__(512)
__attribute__((amdgpu_waves_per_eu(4, 4))) void k3_attn(
    const u64* __restrict__ bits64T, const float* __restrict__ Sl2,
    const float* __restrict__ Dt, const unsigned short* __restrict__ panel,
    float* __restrict__ pacc, float* __restrict__ plsum) {
  const int N = NTOT;
  __shared__ char smem[2 * BUFB];
  int tid = threadIdx.x;
  int w = tid >> 6, l = tid & 63;
  int hd = w & 3, isub = w >> 2;
  int itile = blockIdx.x >> 2, seg = blockIdx.x & 3;
  int ibase = itile * 64 + isub * 32;
  int iblk = itile * 64;
  int m = l & 15, jc = (l >> 4) * 8;
  int i0 = ibase + m, i1 = i0 + 16;
  float sv0 = Sl2[hd * N + i0], sv1 = Sl2[hd * N + i1];
  int seg0 = seg * 32;  // first macro (64-j unit) of this segment

  const char* psrc =
      (const char*)panel + ((size_t)w * 256) * 1024 + (size_t)l * 16;
  const char* dsrc = (const char*)Dt + (size_t)l * 16;
  const u64* bsrc = bits64T + iblk + l;

  f32x4 z4 = {0.f, 0.f, 0.f, 0.f};
  f32x4 acc0[2] = {z4, z4}, acc1[2] = {z4, z4}, acc2[2] = {z4, z4};
  bf16x8 bones;
  {
    u32 pat = (m == 0) ? 0x3f803f80u : 0u;
    u32x4 tmp = {pat, pat, pat, pat};
    bones = *reinterpret_cast<bf16x8*>(&tmp);
  }

  u32x4 Pr0, Pr1, Dr;
  u64 Br;

#define LOADR(t_)                                              \
  {                                                            \
    int tc_ = (t_) > 31 ? 31 : (t_);                           \
    size_t jm_ = (size_t)(seg0 + tc_);                         \
    Pr0 = *(const u32x4*)(psrc + jm_ * 2048);                  \
    Pr1 = *(const u32x4*)(psrc + jm_ * 2048 + 1024);           \
    if (w == 0) Br = bsrc[jm_ * N];                            \
    if (w == 1) Dr = *(const u32x4*)(dsrc + jm_ * 1024);       \
  }

#define DSW(cb_)                                               \
  {                                                            \
    char* b_ = smem + (cb_)*BUFB;                              \
    *(u32x4*)(b_ + w * 2048 + l * 16) = Pr0;                   \
    *(u32x4*)(b_ + w * 2048 + 1024 + l * 16) = Pr1;            \
    if (w == 0) *(u64*)(b_ + 17408 + l * 8) = Br;              \
    if (w == 1) *(u32x4*)(b_ + 16384 + l * 16) = Dr;           \
  }

#define K3_AF(AF, BY, DA, DB, SV)                                        \
  {                                                                      \
    f32x4 xa_ = (DA) + (SV);                                             \
    f32x4 xb_ = (DB) + (SV);                                             \
    f32x4 ya_ = __builtin_elementwise_max(xa_, 0.2f * xa_);              \
    f32x4 yb_ = __builtin_elementwise_max(xb_, 0.2f * xb_);              \
    bf16x8 af_;                                                          \
    _Pragma("unroll") for (int e = 0; e < 4; ++e) af_[e] =               \
        (__bf16)fexp2(ya_[e]);                                           \
    _Pragma("unroll") for (int e = 0; e < 4; ++e) af_[e + 4] =           \
        (__bf16)fexp2(yb_[e]);                                           \
    u32x4 mk_;                                                           \
    _Pragma("unroll") for (int p = 0; p < 4; ++p) {                      \
      u32 lo_ = (u32)(((int)((BY) << (31 - 2 * p))) >> 31);              \
      u32 hi_ = (u32)(((int)((BY) << (30 - 2 * p))) >> 31);              \
      mk_[p] = __builtin_amdgcn_perm(hi_, lo_, 0x07060100u);             \
    }                                                                    \
    u32x4 av_ = *reinterpret_cast<u32x4*>(&af_) & mk_;                   \
    AF = *reinterpret_cast<bf16x8*>(&av_);                               \
  }

#define K3_RG(AF, B0, B1, RG)                                                \
  acc0[RG] =                                                                 \
      __builtin_amdgcn_mfma_f32_16x16x32_bf16(AF, (B0), acc0[RG], 0, 0, 0);  \
  acc1[RG] =                                                                 \
      __builtin_amdgcn_mfma_f32_16x16x32_bf16(AF, (B1), acc1[RG], 0, 0, 0);  \
  acc2[RG] =                                                                 \
      __builtin_amdgcn_mfma_f32_16x16x32_bf16(AF, bones, acc2[RG], 0, 0, 0);

#define COMPUTE(cb_)                                                     \
  {                                                                      \
    const char* b_ = smem + (cb_)*BUFB;                                  \
    u64 w0 = *(const u64*)(b_ + 17408 + (isub * 32 + m) * 8);            \
    u64 w1 = *(const u64*)(b_ + 17408 + (isub * 32 + 16 + m) * 8);       \
    const char* dp_ = b_ + 16384 + hd * 256 + jc * 4;                    \
    f32x4 d0 = *(const f32x4*)(dp_);                                     \
    f32x4 d1 = *(const f32x4*)(dp_ + 16);                                \
    f32x4 d2 = *(const f32x4*)(dp_ + 128);                               \
    f32x4 d3 = *(const f32x4*)(dp_ + 144);                               \
    const char* pp_ = b_ + (hd * 2) * 2048 + l * 16;                     \
    bf16x8 B0a = *(const bf16x8*)(pp_);                                  \
    bf16x8 B0b = *(const bf16x8*)(pp_ + 1024);                           \
    bf16x8 B1a = *(const bf16x8*)(pp_ + 2048);                           \
    bf16x8 B1b = *(const bf16x8*)(pp_ + 3072);                           \
    bf16x8 af_r;                                                         \
    u32 by_;                                                             \
    by_ = ((u32)w0 >> jc) & 0xFFu;                                       \
    K3_AF(af_r, by_, d0, d1, sv0) K3_RG(af_r, B0a, B1a, 0)               \
    by_ = ((u32)w1 >> jc) & 0xFFu;                                       \
    K3_AF(af_r, by_, d0, d1, sv1) K3_RG(af_r, B0a, B1a, 1)               \
    by_ = ((u32)(w0 >> 32) >> jc) & 0xFFu;                               \
    K3_AF(af_r, by_, d2, d3, sv0) K3_RG(af_r, B0b, B1b, 0)               \
    by_ = ((u32)(w1 >> 32) >> jc) & 0xFFu;                               \
    K3_AF(af_r, by_, d2, d3, sv1) K3_RG(af_r, B0b, B1b, 1)               \
  }

  LOADR(0);
  DSW(0);
  LOADR(1);
  __syncthreads();

#pragma unroll 1
  for (int t = 0; t < 32; ++t) {
    int cur = t & 1;
    COMPUTE(cur);
    DSW(cur ^ 1);   // stage macro t+1 (regs loaded last iteration)
    LOADR(t + 2);   // issue global loads for macro t+2 (clamped at tail)
    __syncthreads();
  }
#undef LOADR
#undef DSW
#undef K3_AF
#undef K3_RG
#undef COMPUTE

  // epilogue: D layout col=lane&15 (o), row=(lane>>4)*4+reg (i)
#pragma unroll
  for (int rg = 0; rg < 2; ++rg) {
    int rb = ibase + rg * 16 + ((l >> 4) << 2);
    if (m == 0) {
#pragma unroll
      for (int r = 0; r < 4; ++r)
        plsum[(seg * NH + hd) * N + rb + r] = acc2[rg][r];
    }
#pragma unroll
    for (int r = 0; r < 4; ++r) {
      int row = rb + r;
      pacc[((size_t)seg * N + row) * 128 + hd * 32 + m] = acc0[rg][r];
      pacc[((size_t)seg * N + row) * 128 + hd * 32 + 16 + m] = acc1[rg][r];
    }
  }
}

// ---------------- k4: combine segments + normalize
__global__ __launch_bounds__(256, 2) void k4_combine(
    const float* __restrict__ pacc, const float* __restrict__ plsum,
    float* __restrict__ out) {
  int idx = blockIdx.x * 256 + threadIdx.x;
  int i = idx >> 7;
  int c = idx & 127;
  int hd = c >> 5;
  float a = 0.f, ls = 0.f;
#pragma unroll
  for (int s = 0; s < NSEG; ++s) {
    a += pacc[((size_t)s * NTOT + i) * 128 + c];
    ls += plsum[(s * NH + hd) * NTOT + i];
  }
  out[idx] = (ls > 0.f) ? a / ls : 0.f;
}

extern "C" void kernel_launch(void* const* d_in, const int* in_sizes, int n_in,
                              void* d_out, int out_size, void* d_ws,
                              size_t ws_size, hipStream_t stream) {
  const float* X = (const float*)d_in[0];
  const int* adj = (const int*)d_in[1];
  const float* W = (const float*)d_in[2];
  const float* a_src = (const float*)d_in[3];
  const float* a_dst = (const float*)d_in[4];
  float* out = (float*)d_out;

  char* ws = (char*)d_ws;
  float* h = (float*)(ws + 0x0);                             // 4 MB
  unsigned short* panel = (unsigned short*)(ws + 0x400000);  // 2 MB
  float* Sl2 = (float*)(ws + 0x600000);                      // 128 KB
  float* Dt = (float*)(ws + 0x620000);                       // 128 KB
  u64* bits64T = (u64*)(ws + 0x640000);                      // 8 MB
  float* pacc = (float*)(ws + 0xE40000);                     // 16 MB
  float* plsum = (float*)(ws + 0x1E40000);                   // 512 KB

  k0_pack<<<dim3(1024), dim3(512), 0, stream>>>(adj, bits64T);
  k1_project<<<dim3(256), dim3(256), 0, stream>>>(X, W, h, panel);
  k2_scores<<<dim3(32), dim3(256), 0, stream>>>(h, a_src, a_dst, Sl2, Dt);
  k3_attn<<<dim3(128 * NSEG), dim3(512), 0, stream>>>(bits64T, Sl2, Dt, panel,
                                                      pacc, plsum);
  k4_combine<<<dim3(4096), dim3(256), 0, stream>>>(pacc, plsum, out);
}

// Round 10
// 178.235 us; speedup vs baseline: 1.2985x; 1.0006x over previous
//
#include <hip/hip_runtime.h>
#include <hip/hip_bf16.h>

#define NTOT 8192
#define FIN 128
#define FOUT 32
#define NH 4
#define NSEG 4
#define LOG2E 1.4426950408889634f
// per-wave per-buffer LDS: panel 4K @0, d 256B @4096, bits 512B @4352
#define WBUF 4864

typedef __attribute__((ext_vector_type(4))) float f32x4;
typedef __attribute__((ext_vector_type(4))) unsigned int u32x4;
typedef __attribute__((ext_vector_type(8))) __bf16 bf16x8;
typedef unsigned long long u64;
typedef unsigned int u32;

__device__ __forceinline__ unsigned short f2bf(float x) {
  __hip_bfloat16 h = __float2bfloat16(x);
  return *reinterpret_cast<unsigned short*>(&h);
}

__device__ __forceinline__ float fexp2(float y) {
  float p;
  asm("v_exp_f32 %0, %1" : "=v"(p) : "v"(y));
  return p;
}

// async global->LDS DMA: LDS dst = (wave-uniform base) + lane*size (HW-added);
// global src is per-lane.
__device__ __forceinline__ void dma16(const void* g, void* l) {
  __builtin_amdgcn_global_load_lds(
      (const __attribute__((address_space(1))) void*)g,
      (__attribute__((address_space(3))) void*)l, 16, 0, 0);
}
__device__ __forceinline__ void dma4(const void* g, void* l) {
  __builtin_amdgcn_global_load_lds(
      (const __attribute__((address_space(1))) void*)g,
      (__attribute__((address_space(3))) void*)l, 4, 0, 0);
}

// ---------------- k0: bit-pack adj -> bits64T[j64][i] (u64 per (row,64j)), 8 MB
__global__ __launch_bounds__(512, 2) void k0_pack(
    const int* __restrict__ adj, u64* __restrict__ bits64T) {
  int row = blockIdx.x * 8 + (threadIdx.x >> 6);
  int l = threadIdx.x & 63;
  const int* ap = adj + (size_t)row * NTOT + l;
  u64* bp = bits64T + row;
#pragma unroll 4
  for (int j64 = 0; j64 < NTOT / 64; ++j64) {
    int v = ap[j64 * 64];
    u64 mske = __ballot(v != 0);
    if (l == 0) bp[(size_t)j64 * NTOT] = mske;
  }
}

// ---------------- k1: h = X @ W -> h [N][128] f32, plus B-fragment panels:
// panel[(p*256 + jt)*512 + l*8 + e] (bf16), p = hd*2+half,
//   value = h[node = jt*32 + (l>>4)*8 + e][p*16 + (l&15)]
__global__ __launch_bounds__(256, 2) void k1_project(
    const float* __restrict__ X, const float* __restrict__ W,
    float* __restrict__ h, unsigned short* __restrict__ panel) {
  __shared__ float Xs[32 * 128];
  __shared__ float Ws[32 * 128];
  __shared__ unsigned short Hs[128 * 40];  // [o][node_local], stride 40
  int t = threadIdx.x;
  int nb = blockIdx.x * 32;

  const f32x4* Xg = reinterpret_cast<const f32x4*>(X + (size_t)nb * FIN);
  f32x4* Xs4 = reinterpret_cast<f32x4*>(Xs);
#pragma unroll
  for (int r = 0; r < 4; ++r) Xs4[t + r * 256] = Xg[t + r * 256];

  int ng = t >> 5, oq = t & 31;
  int n0 = ng * 4, o0 = oq * 4;
  f32x4 acc[4];
#pragma unroll
  for (int nn = 0; nn < 4; ++nn) acc[nn] = (f32x4){0.f, 0.f, 0.f, 0.f};

  for (int kp = 0; kp < 4; ++kp) {
    __syncthreads();
#pragma unroll
    for (int r = 0; r < 4; ++r) {
      int q = t + r * 256;
      int flat = q * 4;
      int kk = flat >> 7;
      int c = flat & 127;
      int hdd = c >> 5;
      int oo = c & 31;
      *reinterpret_cast<f32x4*>(&Ws[kk * 128 + c]) =
          *reinterpret_cast<const f32x4*>(W + hdd * (FIN * FOUT) +
                                          (kp * 32 + kk) * FOUT + oo);
    }
    __syncthreads();
#pragma unroll 8
    for (int kk = 0; kk < 32; ++kk) {
      f32x4 wv = *reinterpret_cast<const f32x4*>(&Ws[kk * 128 + o0]);
#pragma unroll
      for (int nn = 0; nn < 4; ++nn)
        acc[nn] += Xs[(n0 + nn) * 128 + kp * 32 + kk] * wv;
    }
  }
#pragma unroll
  for (int nn = 0; nn < 4; ++nn) {
    *reinterpret_cast<f32x4*>(&h[(size_t)(nb + n0 + nn) * 128 + o0]) = acc[nn];
#pragma unroll
    for (int c = 0; c < 4; ++c)
      Hs[(o0 + c) * 40 + (n0 + nn)] = f2bf(acc[nn][c]);
  }
  __syncthreads();
  int jt = blockIdx.x;
#pragma unroll
  for (int it = 0; it < 2; ++it) {
    int item = t + it * 256;
    int p = item >> 6;
    int l = item & 63;
    int o = p * 16 + (l & 15);
    u32x4 v = *reinterpret_cast<const u32x4*>(&Hs[o * 40 + (l >> 4) * 8]);
    *reinterpret_cast<u32x4*>(panel + (size_t)(p * 256 + jt) * 512 + l * 8) = v;
  }
}

// ---------------- k2: per-node scores (x log2e). Sl2 [hd][N]; Dt [jm][hd][64]
__global__ __launch_bounds__(256, 2) void k2_scores(
    const float* __restrict__ h, const float* __restrict__ a_src,
    const float* __restrict__ a_dst, float* __restrict__ Sl2,
    float* __restrict__ Dt) {
  int n = blockIdx.x * 256 + threadIdx.x;
  const f32x4* hv = reinterpret_cast<const f32x4*>(h + (size_t)n * 128);
  const f32x4* as4 = reinterpret_cast<const f32x4*>(a_src);
  const f32x4* ad4 = reinterpret_cast<const f32x4*>(a_dst);
#pragma unroll
  for (int hd = 0; hd < NH; ++hd) {
    f32x4 sa = {0.f, 0.f, 0.f, 0.f}, da = {0.f, 0.f, 0.f, 0.f};
#pragma unroll
    for (int q = 0; q < 8; ++q) {
      f32x4 x = hv[hd * 8 + q];
      sa += x * as4[hd * 8 + q];
      da += x * ad4[hd * 8 + q];
    }
    float s = (sa[0] + sa[1]) + (sa[2] + sa[3]);
    float d = (da[0] + da[1]) + (da[2] + da[3]);
    Sl2[hd * NTOT + n] = s * LOG2E;
    Dt[(n >> 6) * 256 + hd * 64 + (n & 63)] = d * LOG2E;
  }
}

// ---------------- k3: fused masked softmax + PV. 4 waves/block (1 per head),
// M=64 rows/wave, per-wave PRIVATE LDS double-buffer via global_load_lds,
// counted vmcnt(7), ZERO barriers (no inter-wave sharing -> no race).
__global__ __launch_bounds__(256)
__attribute__((amdgpu_waves_per_eu(2, 2))) void k3_attn(
    const u64* __restrict__ bits64T, const float* __restrict__ Sl2,
    const float* __restrict__ Dt, const unsigned short* __restrict__ panel,
    float* __restrict__ pacc, float* __restrict__ plsum) {
  const int N = NTOT;
  __shared__ char smem[4 * 2 * WBUF];  // 38912 B
  int tid = threadIdx.x;
  int hd = tid >> 6, l = tid & 63;
  int itile = blockIdx.x >> 2, seg = blockIdx.x & 3;
  int ibase = itile * 64;
  int m = l & 15, jc = (l >> 4) * 8;
  char* wbase = smem + hd * (2 * WBUF);

  float sv0 = Sl2[hd * N + ibase + m];
  float sv1 = Sl2[hd * N + ibase + 16 + m];
  float sv2 = Sl2[hd * N + ibase + 32 + m];
  float sv3 = Sl2[hd * N + ibase + 48 + m];
  // retire these loads before the first DMA (keeps loop vmcnt counting pure)
  asm volatile("" : "+v"(sv0), "+v"(sv1), "+v"(sv2), "+v"(sv3));
  int seg0 = seg * 32;  // 32 macros (64-j units) per segment

  const char* pg0 = (const char*)panel + (size_t)(hd * 2) * 262144;
  const char* pg1 = pg0 + 262144;
  const char* dg = (const char*)Dt;
  const char* bg = (const char*)bits64T;

  f32x4 z4 = {0.f, 0.f, 0.f, 0.f};
  f32x4 acc0[4] = {z4, z4, z4, z4}, acc1[4] = {z4, z4, z4, z4},
        acc2[4] = {z4, z4, z4, z4};
  bf16x8 bones;
  {
    u32 pat = (m == 0) ? 0x3f803f80u : 0u;
    u32x4 tmp = {pat, pat, pat, pat};
    bones = *reinterpret_cast<bf16x8*>(&tmp);
  }

  // 7 DMAs per stage, all into THIS wave's private region.
#define STAGE(t_)                                                      \
  {                                                                    \
    int tc_ = (t_) > 31 ? 31 : (t_);                                   \
    size_t jm_ = (size_t)(seg0 + tc_);                                 \
    char* lb_ = wbase + ((t_)&1) * WBUF;                               \
    const char* g0_ = pg0 + jm_ * 2048 + (size_t)l * 16;               \
    const char* g1_ = pg1 + jm_ * 2048 + (size_t)l * 16;               \
    dma16(g0_, lb_);                                                   \
    dma16(g0_ + 1024, lb_ + 1024);                                     \
    dma16(g1_, lb_ + 2048);                                            \
    dma16(g1_ + 1024, lb_ + 3072);                                     \
    dma4(dg + jm_ * 1024 + hd * 256 + (size_t)l * 4, lb_ + 4096);      \
    const char* gb_ = bg + (jm_ * N + ibase) * 8;                      \
    dma4(gb_ + (size_t)l * 4, lb_ + 4352);                             \
    dma4(gb_ + 256 + (size_t)l * 4, lb_ + 4608);                       \
  }

  u64 wr0, wr1, wr2, wr3;
  f32x4 d0, d1, d2, d3;
  bf16x8 B0a, B0b, B1a, B1b;

#define LDSREAD(cb_)                                                   \
  {                                                                    \
    const char* b_ = wbase + (cb_)*WBUF;                               \
    wr0 = *(const u64*)(b_ + 4352 + m * 8);                            \
    wr1 = *(const u64*)(b_ + 4352 + 128 + m * 8);                      \
    wr2 = *(const u64*)(b_ + 4352 + 256 + m * 8);                      \
    wr3 = *(const u64*)(b_ + 4352 + 384 + m * 8);                      \
    const char* dp_ = b_ + 4096 + jc * 4;                              \
    d0 = *(const f32x4*)(dp_);                                         \
    d1 = *(const f32x4*)(dp_ + 16);                                    \
    d2 = *(const f32x4*)(dp_ + 128);                                   \
    d3 = *(const f32x4*)(dp_ + 144);                                   \
    const char* pp_ = b_ + (size_t)l * 16;                             \
    B0a = *(const bf16x8*)(pp_);                                       \
    B0b = *(const bf16x8*)(pp_ + 1024);                                \
    B1a = *(const bf16x8*)(pp_ + 2048);                                \
    B1b = *(const bf16x8*)(pp_ + 3072);                                \
  }

#define K3_AF(AF, BY, DA, DB, SV)                                        \
  {                                                                      \
    f32x4 xa_ = (DA) + (SV);                                             \
    f32x4 xb_ = (DB) + (SV);                                             \
    f32x4 ya_ = __builtin_elementwise_max(xa_, 0.2f * xa_);              \
    f32x4 yb_ = __builtin_elementwise_max(xb_, 0.2f * xb_);              \
    bf16x8 af_;                                                          \
    _Pragma("unroll") for (int e = 0; e < 4; ++e) af_[e] =               \
        (__bf16)fexp2(ya_[e]);                                           \
    _Pragma("unroll") for (int e = 0; e < 4; ++e) af_[e + 4] =           \
        (__bf16)fexp2(yb_[e]);                                           \
    u32x4 mk_;                                                           \
    _Pragma("unroll") for (int p = 0; p < 4; ++p) {                      \
      u32 lo_ = (u32)(((int)((BY) << (31 - 2 * p))) >> 31);              \
      u32 hi_ = (u32)(((int)((BY) << (30 - 2 * p))) >> 31);              \
      mk_[p] = __builtin_amdgcn_perm(hi_, lo_, 0x07060100u);             \
    }                                                                    \
    u32x4 av_ = *reinterpret_cast<u32x4*>(&af_) & mk_;                   \
    AF = *reinterpret_cast<bf16x8*>(&av_);                               \
  }

#define MATH_RG(RG, WR, SV)                                                  \
  {                                                                          \
    bf16x8 af_r;                                                             \
    u32 by_ = ((u32)(WR) >> jc) & 0xFFu;                                     \
    K3_AF(af_r, by_, d0, d1, SV)                                             \
    acc0[RG] =                                                               \
        __builtin_amdgcn_mfma_f32_16x16x32_bf16(af_r, B0a, acc0[RG], 0, 0, 0); \
    acc1[RG] =                                                               \
        __builtin_amdgcn_mfma_f32_16x16x32_bf16(af_r, B1a, acc1[RG], 0, 0, 0); \
    acc2[RG] = __builtin_amdgcn_mfma_f32_16x16x32_bf16(af_r, bones,          \
                                                       acc2[RG], 0, 0, 0);   \
    by_ = ((u32)((WR) >> 32) >> jc) & 0xFFu;                                 \
    K3_AF(af_r, by_, d2, d3, SV)                                             \
    acc0[RG] =                                                               \
        __builtin_amdgcn_mfma_f32_16x16x32_bf16(af_r, B0b, acc0[RG], 0, 0, 0); \
    acc1[RG] =                                                               \
        __builtin_amdgcn_mfma_f32_16x16x32_bf16(af_r, B1b, acc1[RG], 0, 0, 0); \
    acc2[RG] = __builtin_amdgcn_mfma_f32_16x16x32_bf16(af_r, bones,          \
                                                       acc2[RG], 0, 0, 0);   \
  }

  STAGE(0)
  STAGE(1)

#pragma unroll 1
  for (int t = 0; t < 32; ++t) {
    int cur = t & 1;
    // wait for the OLDEST 7 (stage t); stage t+1's 7 stay in flight
    asm volatile("s_waitcnt vmcnt(7)" ::: "memory");
    LDSREAD(cur)
    // ds_reads retired before this slot is re-staged below
    asm volatile("s_waitcnt lgkmcnt(0)" ::: "memory");
    __builtin_amdgcn_sched_barrier(0);
    STAGE(t + 2)
    MATH_RG(0, wr0, sv0)
    MATH_RG(1, wr1, sv1)
    MATH_RG(2, wr2, sv2)
    MATH_RG(3, wr3, sv3)
  }
#undef STAGE
#undef LDSREAD
#undef K3_AF
#undef MATH_RG

  // drain outstanding LDS-DMAs before the wave can exit / LDS is reused
  asm volatile("s_waitcnt vmcnt(0)" ::: "memory");

  // epilogue: D layout col=lane&15 (o), row=(lane>>4)*4+reg (i)
#pragma unroll
  for (int rg = 0; rg < 4; ++rg) {
    int rb = ibase + rg * 16 + ((l >> 4) << 2);
    if (m == 0) {
#pragma unroll
      for (int r = 0; r < 4; ++r)
        plsum[(seg * NH + hd) * N + rb + r] = acc2[rg][r];
    }
#pragma unroll
    for (int r = 0; r < 4; ++r) {
      int row = rb + r;
      pacc[((size_t)seg * N + row) * 128 + hd * 32 + m] = acc0[rg][r];
      pacc[((size_t)seg * N + row) * 128 + hd * 32 + 16 + m] = acc1[rg][r];
    }
  }
}

// ---------------- k4: combine segments + normalize
__global__ __launch_bounds__(256, 2) void k4_combine(
    const float* __restrict__ pacc, const float* __restrict__ plsum,
    float* __restrict__ out) {
  int idx = blockIdx.x * 256 + threadIdx.x;
  int i = idx >> 7;
  int c = idx & 127;
  int hd = c >> 5;
  float a = 0.f, ls = 0.f;
#pragma unroll
  for (int s = 0; s < NSEG; ++s) {
    a += pacc[((size_t)s * NTOT + i) * 128 + c];
    ls += plsum[(s * NH + hd) * NTOT + i];
  }
  out[idx] = (ls > 0.f) ? a / ls : 0.f;
}

extern "C" void kernel_launch(void* const* d_in, const int* in_sizes, int n_in,
                              void* d_out, int out_size, void* d_ws,
                              size_t ws_size, hipStream_t stream) {
  const float* X = (const float*)d_in[0];
  const int* adj = (const int*)d_in[1];
  const float* W = (const float*)d_in[2];
  const float* a_src = (const float*)d_in[3];
  const float* a_dst = (const float*)d_in[4];
  float* out = (float*)d_out;

  char* ws = (char*)d_ws;
  float* h = (float*)(ws + 0x0);                             // 4 MB
  unsigned short* panel = (unsigned short*)(ws + 0x400000);  // 2 MB
  float* Sl2 = (float*)(ws + 0x600000);                      // 128 KB
  float* Dt = (float*)(ws + 0x620000);                       // 128 KB
  u64* bits64T = (u64*)(ws + 0x640000);                      // 8 MB
  float* pacc = (float*)(ws + 0xE40000);                     // 16 MB
  float* plsum = (float*)(ws + 0x1E40000);                   // 512 KB

  k0_pack<<<dim3(1024), dim3(512), 0, stream>>>(adj, bits64T);
  k1_project<<<dim3(256), dim3(256), 0, stream>>>(X, W, h, panel);
  k2_scores<<<dim3(32), dim3(256), 0, stream>>>(h, a_src, a_dst, Sl2, Dt);
  k3_attn<<<dim3(128 * NSEG), dim3(256), 0, stream>>>(bits64T, Sl2, Dt, panel,
                                                      pacc, plsum);
  k4_combine<<<dim3(4096), dim3(256), 0, stream>>>(pacc, plsum, out);
}

// Round 11
// 146.468 us; speedup vs baseline: 1.5802x; 1.2169x over previous
//
#include <hip/hip_runtime.h>
#include <hip/hip_bf16.h>

#define NTOT 8192
#define FIN 128
#define FOUT 32
#define NH 4
#define NSEG 4
#define SEGJ (NTOT / NSEG)  // 2048
#define LOG2E 1.4426950408889634f

typedef __attribute__((ext_vector_type(4))) float f32x4;
typedef __attribute__((ext_vector_type(4))) int i32x4;
typedef __attribute__((ext_vector_type(4))) unsigned int u32x4;
typedef __attribute__((ext_vector_type(8))) __bf16 bf16x8;
typedef unsigned long long u64;
typedef unsigned int u32;

__device__ __forceinline__ unsigned short f2bf(float x) {
  __hip_bfloat16 h = __float2bfloat16(x);
  return *reinterpret_cast<unsigned short*>(&h);
}

__device__ __forceinline__ float fexp2(float y) {
  float p;
  asm("v_exp_f32 %0, %1" : "=v"(p) : "v"(y));
  return p;
}

// ---------------- k1: h = X @ W -> h [N][128] f32, plus B-fragment panels:
// panel[(p*256 + jt)*512 + l*8 + e] (bf16), p = hd*2+half,
//   value = h[node = jt*32 + (l>>4)*8 + e][p*16 + (l&15)]
__global__ __launch_bounds__(256, 2) void k1_project(
    const float* __restrict__ X, const float* __restrict__ W,
    float* __restrict__ h, unsigned short* __restrict__ panel) {
  __shared__ float Xs[32 * 128];
  __shared__ float Ws[32 * 128];
  __shared__ unsigned short Hs[128 * 40];  // [o][node_local], stride 40
  int t = threadIdx.x;
  int nb = blockIdx.x * 32;

  const f32x4* Xg = reinterpret_cast<const f32x4*>(X + (size_t)nb * FIN);
  f32x4* Xs4 = reinterpret_cast<f32x4*>(Xs);
#pragma unroll
  for (int r = 0; r < 4; ++r) Xs4[t + r * 256] = Xg[t + r * 256];

  int ng = t >> 5, oq = t & 31;
  int n0 = ng * 4, o0 = oq * 4;
  f32x4 acc[4];
#pragma unroll
  for (int nn = 0; nn < 4; ++nn) acc[nn] = (f32x4){0.f, 0.f, 0.f, 0.f};

  for (int kp = 0; kp < 4; ++kp) {
    __syncthreads();
#pragma unroll
    for (int r = 0; r < 4; ++r) {
      int q = t + r * 256;
      int flat = q * 4;
      int kk = flat >> 7;
      int c = flat & 127;
      int hdd = c >> 5;
      int oo = c & 31;
      *reinterpret_cast<f32x4*>(&Ws[kk * 128 + c]) =
          *reinterpret_cast<const f32x4*>(W + hdd * (FIN * FOUT) +
                                          (kp * 32 + kk) * FOUT + oo);
    }
    __syncthreads();
#pragma unroll 8
    for (int kk = 0; kk < 32; ++kk) {
      f32x4 wv = *reinterpret_cast<const f32x4*>(&Ws[kk * 128 + o0]);
#pragma unroll
      for (int nn = 0; nn < 4; ++nn)
        acc[nn] += Xs[(n0 + nn) * 128 + kp * 32 + kk] * wv;
    }
  }
#pragma unroll
  for (int nn = 0; nn < 4; ++nn) {
    *reinterpret_cast<f32x4*>(&h[(size_t)(nb + n0 + nn) * 128 + o0]) = acc[nn];
#pragma unroll
    for (int c = 0; c < 4; ++c)
      Hs[(o0 + c) * 40 + (n0 + nn)] = f2bf(acc[nn][c]);
  }
  __syncthreads();
  int jt = blockIdx.x;
#pragma unroll
  for (int it = 0; it < 2; ++it) {
    int item = t + it * 256;
    int p = item >> 6;
    int l = item & 63;
    int o = p * 16 + (l & 15);
    u32x4 v = *reinterpret_cast<const u32x4*>(&Hs[o * 40 + (l >> 4) * 8]);
    *reinterpret_cast<u32x4*>(panel + (size_t)(p * 256 + jt) * 512 + l * 8) = v;
  }
}

// ---------------- k2: per-node scores (x log2e). Sl2 [hd][N]; Dt [jm][hd][64]
__global__ __launch_bounds__(256, 2) void k2_scores(
    const float* __restrict__ h, const float* __restrict__ a_src,
    const float* __restrict__ a_dst, float* __restrict__ Sl2,
    float* __restrict__ Dt) {
  int n = blockIdx.x * 256 + threadIdx.x;
  const f32x4* hv = reinterpret_cast<const f32x4*>(h + (size_t)n * 128);
  const f32x4* as4 = reinterpret_cast<const f32x4*>(a_src);
  const f32x4* ad4 = reinterpret_cast<const f32x4*>(a_dst);
#pragma unroll
  for (int hd = 0; hd < NH; ++hd) {
    f32x4 sa = {0.f, 0.f, 0.f, 0.f}, da = {0.f, 0.f, 0.f, 0.f};
#pragma unroll
    for (int q = 0; q < 8; ++q) {
      f32x4 x = hv[hd * 8 + q];
      sa += x * as4[hd * 8 + q];
      da += x * ad4[hd * 8 + q];
    }
    float s = (sa[0] + sa[1]) + (sa[2] + sa[3]);
    float d = (da[0] + da[1]) + (da[2] + da[3]);
    Sl2[hd * NTOT + n] = s * LOG2E;
    Dt[(n >> 6) * 256 + hd * 64 + (n & 63)] = d * LOG2E;
  }
}

// ---------------- k3: fused adj-read + masked softmax + PV.
// 4 waves/block; wave w = rows [ibase+w*16, +16) x ALL 4 heads, so the adj
// stream (268 MB, the only HBM-scale input) is read exactly once.
// No LDS; B/d tables are L1-resident; adj prefetched 2 macros deep (pinned).
__global__ __launch_bounds__(256)
__attribute__((amdgpu_waves_per_eu(2, 2))) void k3_attn(
    const int* __restrict__ adj, const float* __restrict__ Sl2,
    const float* __restrict__ Dt, const unsigned short* __restrict__ panel,
    float* __restrict__ pacc, float* __restrict__ plsum) {
  const int N = NTOT;
  int tid = threadIdx.x;
  int w = tid >> 6, l = tid & 63;
  int itile = blockIdx.x >> 2, seg = blockIdx.x & 3;
  int ibase = itile * 64;
  int m = l & 15, g = l >> 4, jc = g * 8;
  int row = ibase + w * 16 + m;
  int seg0 = seg * 32;  // first 64-j macro of this segment

  float svv[4];
#pragma unroll
  for (int hd = 0; hd < 4; ++hd) svv[hd] = Sl2[hd * N + row];

  const int* adjr = adj + (size_t)row * N + seg * SEGJ + jc;

  f32x4 z4 = {0.f, 0.f, 0.f, 0.f};
  f32x4 c0[4] = {z4, z4, z4, z4}, c1[4] = {z4, z4, z4, z4},
        cs[4] = {z4, z4, z4, z4};
  bf16x8 bones;
  {
    u32 pat = (m == 0) ? 0x3f803f80u : 0u;
    u32x4 tmp = {pat, pat, pat, pat};
    bones = *reinterpret_cast<bf16x8*>(&tmp);
  }

  i32x4 Aa0, Aa1, Aa2, Aa3, Ba0, Ba1, Ba2, Ba3;

  // adj prefetch for macro t_ (pinned so it cannot be sunk)
#define AISS(P, t_)                                            \
  {                                                            \
    int tc_ = (t_) > 31 ? 31 : (t_);                           \
    const int* a_ = adjr + tc_ * 64;                           \
    P##a0 = *reinterpret_cast<const i32x4*>(a_);               \
    P##a1 = *reinterpret_cast<const i32x4*>(a_ + 4);           \
    P##a2 = *reinterpret_cast<const i32x4*>(a_ + 32);          \
    P##a3 = *reinterpret_cast<const i32x4*>(a_ + 36);          \
  }                                                            \
  __builtin_amdgcn_sched_barrier(0);

  // masked A-frag: y = LeakyReLU(s+d)*log2e, gated to -1e9 by adj, exp2
#define AFSEL(AF, AV0, AV1, DA, DB, SV)                                  \
  {                                                                      \
    f32x4 xa_ = (DA) + (SV);                                             \
    f32x4 xb_ = (DB) + (SV);                                             \
    f32x4 ya_ = __builtin_elementwise_max(xa_, 0.2f * xa_);              \
    f32x4 yb_ = __builtin_elementwise_max(xb_, 0.2f * xb_);              \
    _Pragma("unroll") for (int e = 0; e < 4; ++e) {                      \
      float y_ = ((AV0)[e] != 0) ? ya_[e] : -1e9f;                       \
      AF[e] = (__bf16)fexp2(y_);                                         \
    }                                                                    \
    _Pragma("unroll") for (int e = 0; e < 4; ++e) {                      \
      float y_ = ((AV1)[e] != 0) ? yb_[e] : -1e9f;                       \
      AF[e + 4] = (__bf16)fexp2(y_);                                     \
    }                                                                    \
  }

#define MFM(AF, B, ACC) \
  ACC = __builtin_amdgcn_mfma_f32_16x16x32_bf16(AF, B, ACC, 0, 0, 0);

  // full macro: 4 heads x (2 k-halves x 3 MFMA)
#define MATHM(P, t_)                                                       \
  {                                                                       \
    int jm_ = seg0 + (t_);                                                \
    const float* db_ = Dt + (size_t)jm_ * 256;                            \
    const unsigned short* pb_ =                                           \
        panel + (size_t)(seg * 64 + (t_)*2) * 512 + l * 8;                \
    _Pragma("unroll") for (int hd = 0; hd < 4; ++hd) {                    \
      f32x4 d0 = *(const f32x4*)(db_ + hd * 64 + jc);                     \
      f32x4 d1 = *(const f32x4*)(db_ + hd * 64 + jc + 4);                 \
      f32x4 d2 = *(const f32x4*)(db_ + hd * 64 + 32 + jc);                \
      f32x4 d3 = *(const f32x4*)(db_ + hd * 64 + 32 + jc + 4);            \
      const unsigned short* p0_ = pb_ + (size_t)(hd * 2) * 131072;        \
      const unsigned short* p1_ = pb_ + (size_t)(hd * 2 + 1) * 131072;    \
      bf16x8 B0a = *(const bf16x8*)(p0_);                                 \
      bf16x8 B1a = *(const bf16x8*)(p1_);                                 \
      bf16x8 B0b = *(const bf16x8*)(p0_ + 512);                           \
      bf16x8 B1b = *(const bf16x8*)(p1_ + 512);                           \
      float sv_ = svv[hd];                                                \
      bf16x8 af_;                                                         \
      AFSEL(af_, P##a0, P##a1, d0, d1, sv_)                               \
      MFM(af_, B0a, c0[hd]) MFM(af_, B1a, c1[hd]) MFM(af_, bones, cs[hd]) \
      AFSEL(af_, P##a2, P##a3, d2, d3, sv_)                               \
      MFM(af_, B0b, c0[hd]) MFM(af_, B1b, c1[hd]) MFM(af_, bones, cs[hd]) \
    }                                                                     \
  }

  AISS(A, 0)
  AISS(B, 1)
#pragma unroll 1
  for (int tt = 0; tt < 16; ++tt) {
    MATHM(A, 2 * tt)
    AISS(A, 2 * tt + 2)
    MATHM(B, 2 * tt + 1)
    AISS(B, 2 * tt + 3)
  }
#undef AISS
#undef AFSEL
#undef MFM
#undef MATHM

  // epilogue: D layout col=lane&15 (o), row=(lane>>4)*4+reg (i)
#pragma unroll
  for (int hd = 0; hd < 4; ++hd) {
    int rb = ibase + w * 16 + g * 4;
    if (m == 0) {
#pragma unroll
      for (int r = 0; r < 4; ++r)
        plsum[(seg * NH + hd) * N + rb + r] = cs[hd][r];
    }
#pragma unroll
    for (int r = 0; r < 4; ++r) {
      int rowr = rb + r;
      pacc[((size_t)seg * N + rowr) * 128 + hd * 32 + m] = c0[hd][r];
      pacc[((size_t)seg * N + rowr) * 128 + hd * 32 + 16 + m] = c1[hd][r];
    }
  }
}

// ---------------- k4: combine segments + normalize
__global__ __launch_bounds__(256, 2) void k4_combine(
    const float* __restrict__ pacc, const float* __restrict__ plsum,
    float* __restrict__ out) {
  int idx = blockIdx.x * 256 + threadIdx.x;
  int i = idx >> 7;
  int c = idx & 127;
  int hd = c >> 5;
  float a = 0.f, ls = 0.f;
#pragma unroll
  for (int s = 0; s < NSEG; ++s) {
    a += pacc[((size_t)s * NTOT + i) * 128 + c];
    ls += plsum[(s * NH + hd) * NTOT + i];
  }
  out[idx] = (ls > 0.f) ? a / ls : 0.f;
}

extern "C" void kernel_launch(void* const* d_in, const int* in_sizes, int n_in,
                              void* d_out, int out_size, void* d_ws,
                              size_t ws_size, hipStream_t stream) {
  const float* X = (const float*)d_in[0];
  const int* adj = (const int*)d_in[1];
  const float* W = (const float*)d_in[2];
  const float* a_src = (const float*)d_in[3];
  const float* a_dst = (const float*)d_in[4];
  float* out = (float*)d_out;

  char* ws = (char*)d_ws;
  float* h = (float*)(ws + 0x0);                             // 4 MB
  unsigned short* panel = (unsigned short*)(ws + 0x400000);  // 2 MB
  float* Sl2 = (float*)(ws + 0x600000);                      // 128 KB
  float* Dt = (float*)(ws + 0x620000);                       // 128 KB
  float* pacc = (float*)(ws + 0xE40000);                     // 16 MB
  float* plsum = (float*)(ws + 0x1E40000);                   // 512 KB

  k1_project<<<dim3(256), dim3(256), 0, stream>>>(X, W, h, panel);
  k2_scores<<<dim3(32), dim3(256), 0, stream>>>(h, a_src, a_dst, Sl2, Dt);
  k3_attn<<<dim3(128 * NSEG), dim3(256), 0, stream>>>(adj, Sl2, Dt, panel,
                                                      pacc, plsum);
  k4_combine<<<dim3(4096), dim3(256), 0, stream>>>(pacc, plsum, out);
}